// Round 5
// baseline (956.646 us; speedup 1.0000x reference)
//
#include <hip/hip_runtime.h>
#include <cstdint>
#include <cstddef>

#define H_DIM 2560
#define I_DIM 6912
#define NTOK  8192   // B*S = 4*2048

typedef __attribute__((ext_vector_type(8))) __bf16 bf16x8;
typedef __attribute__((ext_vector_type(4))) float  f32x4;
typedef __attribute__((ext_vector_type(16))) float f32x16;

// ---- async global->LDS, 16B per lane -------------------------------------
__device__ inline void gld16(void* lds, const void* g) {
    __builtin_amdgcn_global_load_lds(
        (__attribute__((address_space(1))) void*)(void*)g,
        (__attribute__((address_space(3))) void*)lds, 16, 0, 0);
}

// ---- prep: f32 -> bf16 (8 elems/thread) ----------------------------------
__global__ __launch_bounds__(256) void cvt_x_kernel(const float* __restrict__ x,
                                                    __bf16* __restrict__ xb, int n8) {
    int gid = blockIdx.x * 256 + threadIdx.x;
    if (gid >= n8) return;
    const float4* p = (const float4*)(x + (size_t)gid * 8);
    float4 v0 = p[0], v1 = p[1];
    bf16x8 o;
    o[0] = (__bf16)v0.x; o[1] = (__bf16)v0.y; o[2] = (__bf16)v0.z; o[3] = (__bf16)v0.w;
    o[4] = (__bf16)v1.x; o[5] = (__bf16)v1.y; o[6] = (__bf16)v1.z; o[7] = (__bf16)v1.w;
    *(bf16x8*)(xb + (size_t)gid * 8) = o;
}

// ---- prep: unpack SIMD-interleaved 2-bit ternary -> bf16 ------------------
// mode 0: dst row = i; mode 1/2: 32-row gate/up interleave for combined B'
__global__ __launch_bounds__(256) void unpack_w_kernel(const int* __restrict__ packed,
                                                       __bf16* __restrict__ out,
                                                       int M, int K,
                                                       const float* __restrict__ norm,
                                                       int mode) {
    int gid = blockIdx.x * 256 + threadIdx.x;
    int per_row = K >> 3;
    if (gid >= M * per_row) return;
    int i  = gid / per_row;
    int k0 = (gid % per_row) * 8;
    int blk = k0 >> 7;
    int grp = (k0 >> 5) & 3;
    int j0  = k0 & 31;
    int shift = 6 - 2 * grp;
    const int* p = packed + (size_t)i * (K >> 2) + blk * 32 + j0;
    int4 v0 = *(const int4*)p;
    int4 v1 = *(const int4*)(p + 4);
    int vals[8] = {v0.x, v0.y, v0.z, v0.w, v1.x, v1.y, v1.z, v1.w};
    bf16x8 o;
#pragma unroll
    for (int b = 0; b < 8; ++b) {
        float f = (float)(((vals[b] >> shift) & 3) - 1);
        if (norm) f *= norm[k0 + b];
        o[b] = (__bf16)f;
    }
    int dst = (mode == 0) ? i : ((i >> 5) * 64 + (i & 31) + ((mode == 2) ? 32 : 0));
    *(bf16x8*)(out + (size_t)dst * K + k0) = o;
}

// ---- per-token rsqrt(mean(hidden^2)+eps) ----------------------------------
__global__ __launch_bounds__(256) void rms_rs_kernel(const __bf16* __restrict__ hidden,
                                                     float* __restrict__ rs) {
    const int tk = blockIdx.x;
    const __bf16* row = hidden + (size_t)tk * I_DIM;
    float s = 0.f;
    for (int idx = threadIdx.x; idx < I_DIM / 8; idx += 256) {
        bf16x8 v = *(const bf16x8*)&row[idx * 8];
#pragma unroll
        for (int j = 0; j < 8; ++j) { float f = (float)v[j]; s += f * f; }
    }
#pragma unroll
    for (int off = 32; off; off >>= 1) s += __shfl_down(s, off, 64);
    __shared__ float wsum[4];
    if ((threadIdx.x & 63) == 0) wsum[threadIdx.x >> 6] = s;
    __syncthreads();
    if (threadIdx.x == 0) {
        float tot = wsum[0] + wsum[1] + wsum[2] + wsum[3];
        rs[tk] = rsqrtf(tot / (float)I_DIM + 1e-6f);
    }
}

// ===========================================================================
// 256x256 fused gate+up GEMM, 32x32x16 MFMA, 2 phases/K-tile.
// 8 waves (2M x 4N), per-wave 128x64: 4 mfrag x 2 nfrag of 32x32.
// LDS 128KiB = 2 buf x {A-kk0, A-kk1, B-kk0, B-kk1} 16KB quarters
// (quarter = 256 rows x 32 K, stored as 128 row-pair lines of 128B,
//  slot' = ((row&1)<<2 | sub) ^ ((row>>1)&7), sub = 16B index in 64B half).
// Stage slots: Ph1 -> (kt+1).{Bk1,Akk1}; Ph2 -> (kt+2).{Akk0,Bk0}; vmcnt(4)
// at tile boundary drains exactly tile kt+1's 4 quarters (ledger verified).
// nfrag0 = gate cols, nfrag1 = up cols (32-row interleaved B').
// ===========================================================================
template<int KDIM>
__global__ __launch_bounds__(512, 2) void gemm_gu32(
    const __bf16* __restrict__ A,      // [NTOK][KDIM]
    const __bf16* __restrict__ B,      // [2*I][KDIM] gate/up 32-row interleave
    const float* __restrict__ gs_p,
    const float* __restrict__ us_p,
    __bf16* __restrict__ hidden,       // [NTOK][I_DIM]
    int nby)
{
    constexpr int KB = KDIM * 2;
    constexpr int NT = KDIM / 64;
    __shared__ __align__(16) char smem[131072];

    // bijective XCD swizzle (grid % 8 == 0)
    const int nwg = (int)gridDim.x;
    const int q = nwg >> 3;
    const int id = (int)blockIdx.x;
    const int wg = (id & 7) * q + (id >> 3);
    const int bx = wg / nby, by = wg % nby;
    const int m0 = bx * 256, n0 = by * 256;

    const int t = (int)threadIdx.x;
    const int lane = t & 63;
    const int wid = t >> 6;
    const int wm = wid >> 2, wn = wid & 3;
    const int l31 = lane & 31, lh = lane >> 5;

    // ---- staging map: linear LDS dest, inverse-swizzled global source ------
    const int qa  = (t & 7) ^ ((t >> 3) & 7);       // logical (row&1)<<2|sub
    const int rA2 = ((t >> 3) << 1) + (qa >> 2);    // row within 128-group
    const int cb  = (qa & 3) * 16;                  // byte within 64B K-half
    const char* gA0 = (const char*)A + (size_t)(m0 + rA2) * KB + cb;
    const char* gA1 = (const char*)A + (size_t)(m0 + 128 + rA2) * KB + cb;
    const char* gB0 = (const char*)B + (size_t)(n0 + rA2) * KB + cb;
    const char* gB1 = (const char*)B + (size_t)(n0 + 128 + rA2) * KB + cb;
    char* ldst = smem + t * 16;

    // ---- compute-side read offsets (swizzled) ------------------------------
    const int abase = (wm * 64 + (l31 >> 1)) * 128;
    const int bbase = (wn * 32 + (l31 >> 1)) * 128;
    const int xr = (lane >> 1) & 7;
    const int sl0 = ((((lane & 1) << 2) | (0 + lh)) ^ xr) << 4;  // kst=0
    const int sl1 = ((((lane & 1) << 2) | (2 + lh)) ^ xr) << 4;  // kst=1

    f32x16 acc[4][2];
#pragma unroll
    for (int mf = 0; mf < 4; ++mf)
#pragma unroll
        for (int nf = 0; nf < 2; ++nf)
#pragma unroll
            for (int r = 0; r < 16; ++r) acc[mf][nf][r] = 0.f;

#define STG_A(d, kt, kk) do {                                                  \
        gld16(ldst + (d) * 65536 + (kk) * 16384,                               \
              gA0 + (size_t)(kt) * 128 + (kk) * 64);                           \
        gld16(ldst + (d) * 65536 + (kk) * 16384 + 8192,                        \
              gA1 + (size_t)(kt) * 128 + (kk) * 64);                           \
    } while (0)
#define STG_B(d, kt, kk) do {                                                  \
        gld16(ldst + (d) * 65536 + 32768 + (kk) * 16384,                       \
              gB0 + (size_t)(kt) * 128 + (kk) * 64);                           \
        gld16(ldst + (d) * 65536 + 32768 + (kk) * 16384 + 8192,                \
              gB1 + (size_t)(kt) * 128 + (kk) * 64);                           \
    } while (0)
#define PHASE_LOAD(d, kk) do {                                                 \
        const char* _ba = smem + (d) * 65536 + (kk) * 16384;                   \
        _Pragma("unroll")                                                      \
        for (int _mf = 0; _mf < 4; ++_mf) {                                    \
            a[_mf][0] = *(const bf16x8*)(_ba + abase + _mf * 2048 + sl0);      \
            a[_mf][1] = *(const bf16x8*)(_ba + abase + _mf * 2048 + sl1);      \
        }                                                                      \
        const char* _bb = smem + (d) * 65536 + 32768 + (kk) * 16384;           \
        _Pragma("unroll")                                                      \
        for (int _nf = 0; _nf < 2; ++_nf) {                                    \
            b[_nf][0] = *(const bf16x8*)(_bb + bbase + _nf * 2048 + sl0);      \
            b[_nf][1] = *(const bf16x8*)(_bb + bbase + _nf * 2048 + sl1);      \
        }                                                                      \
    } while (0)
#define PHASE_MMA() do { __builtin_amdgcn_s_setprio(1);                        \
        _Pragma("unroll")                                                      \
        for (int _ks = 0; _ks < 2; ++_ks)                                      \
        _Pragma("unroll")                                                      \
        for (int _mf = 0; _mf < 4; ++_mf)                                      \
        _Pragma("unroll")                                                      \
        for (int _nf = 0; _nf < 2; ++_nf)                                      \
            acc[_mf][_nf] = __builtin_amdgcn_mfma_f32_32x32x16_bf16(           \
                a[_mf][_ks], b[_nf][_ks], acc[_mf][_nf], 0, 0, 0);             \
        __builtin_amdgcn_s_setprio(0); } while (0)
#define BAR() do { asm volatile("" ::: "memory");                              \
        __builtin_amdgcn_s_barrier();                                          \
        asm volatile("" ::: "memory"); } while (0)

    // ---- prologue: tile0 all 4 quarters + tile1 {Akk0, Bk0} ----------------
    STG_A(0, 0, 0); STG_A(0, 0, 1); STG_B(0, 0, 0); STG_B(0, 0, 1);
    STG_A(1, 1, 0); STG_B(1, 1, 0);
    asm volatile("s_waitcnt vmcnt(4)" ::: "memory");
    BAR();

    bf16x8 a[4][2], b[2][2];
    for (int kt = 0; kt < NT; ++kt) {
        const int d = kt & 1;
        // Ph1 (kk0): stage (kt+1).{Bk1, Akk1}
        PHASE_LOAD(d, 0);
        if (kt + 1 < NT) { STG_B(d ^ 1, kt + 1, 1); STG_A(d ^ 1, kt + 1, 1); }
        BAR(); PHASE_MMA(); BAR();
        // Ph2 (kk1): stage (kt+2).{Akk0, Bk0} + tile-boundary counted vmcnt
        PHASE_LOAD(d, 1);
        if (kt + 2 < NT) {
            STG_A(d, kt + 2, 0); STG_B(d, kt + 2, 0);
            asm volatile("s_waitcnt vmcnt(4)" ::: "memory");
        } else {
            asm volatile("s_waitcnt vmcnt(0)" ::: "memory");
        }
        BAR(); PHASE_MMA(); BAR();
    }

#undef STG_A
#undef STG_B
#undef PHASE_LOAD
#undef PHASE_MMA
#undef BAR

    // ---- epilogue: hidden = gs^2*us * relu(g)^2 * u ------------------------
    // C map (32x32): col = lane&31, row = (reg&3) + 8*(reg>>2) + 4*(lane>>5)
    const float comb = gs_p[0] * gs_p[0] * us_p[0];
    const int colg = by * 128 + wn * 32 + l31;
#pragma unroll
    for (int mf = 0; mf < 4; ++mf)
#pragma unroll
        for (int reg = 0; reg < 16; ++reg) {
            const int rowl = (reg & 3) + 8 * (reg >> 2) + 4 * lh;
            const int row = m0 + wm * 128 + mf * 32 + rowl;
            float g = acc[mf][0][reg];
            float u = acc[mf][1][reg];
            float r = fmaxf(g, 0.f);
            hidden[(size_t)row * I_DIM + colg] = (__bf16)(comb * r * r * u);
        }
}

// ===========================================================================
// Down GEMM: R3-proven triple-buffer skeleton, 32x32x16 MFMA frags.
// BM=256, BN=128, BK=64, 8 waves (4M x 2N), per-wave 64x64: 2mf x 2nf.
// ===========================================================================
template<int KDIM>
__global__ __launch_bounds__(512) void gemm_down_pipe(
    const __bf16* __restrict__ A,      // hidden [NTOK][KDIM]
    const __bf16* __restrict__ B,      // Wd [H][KDIM] (norm_w folded)
    const float* __restrict__ ds_p,
    const float* __restrict__ rs,
    float* __restrict__ outf,
    int nby)
{
    constexpr int BM = 256, BN = 128, BK = 64;
    constexpr int NT = KDIM / BK;
    constexpr int SLOTB = (BM + BN) * BK * 2;
    __shared__ __align__(16) char smem[3 * SLOTB];

    const int nwg = (int)gridDim.x;
    const int q = nwg >> 3;
    const int id = (int)blockIdx.x;
    const int wg = (id & 7) * q + (id >> 3);
    const int bx = wg / nby;
    const int by = wg % nby;

    const int m0 = bx * BM;
    const int n0 = by * BN;
    const int t  = (int)threadIdx.x;
    const int lane = t & 63;
    const int wm = (t >> 6) >> 1;   // 0..3
    const int wn = (t >> 6) & 1;    // 0..1
    const int l31 = lane & 31, lh = lane >> 5;
    const int sx = lane & 7;        // row&7 for frag reads

    const int srow = t >> 3;
    const int scol = ((t & 7) * 16) ^ ((srow & 7) << 4);
    const char* gA = (const char*)A + (size_t)(m0 + srow) * (KDIM * 2) + scol;
    const char* gB = (const char*)B + (size_t)(n0 + srow) * (KDIM * 2) + scol;
    char* lbase = smem + t * 16;

    f32x16 acc[2][2];
#pragma unroll
    for (int mf = 0; mf < 2; ++mf)
#pragma unroll
        for (int nf = 0; nf < 2; ++nf)
#pragma unroll
            for (int r = 0; r < 16; ++r) acc[mf][nf][r] = 0.f;

#define STAGE_T(s, kt) do {                                                     \
        char* _ls = lbase + (s) * SLOTB;                                        \
        const char* _ga = gA + (kt) * (BK * 2);                                 \
        _Pragma("unroll")                                                       \
        for (int _i = 0; _i < 4; ++_i)                                          \
            gld16(_ls + _i * 8192, _ga + (size_t)_i * 64 * (KDIM * 2));         \
        const char* _gb = gB + (kt) * (BK * 2);                                 \
        char* _lb = _ls + BM * BK * 2;                                          \
        _Pragma("unroll")                                                       \
        for (int _i = 0; _i < 2; ++_i)                                          \
            gld16(_lb + _i * 8192, _gb + (size_t)_i * 64 * (KDIM * 2));         \
    } while (0)

#define COMPUTE_T(s) do {                                                       \
        const char* _sa = smem + (s) * SLOTB;                                   \
        const char* _sb = _sa + BM * BK * 2;                                    \
        _Pragma("unroll")                                                       \
        for (int _ks = 0; _ks < 4; ++_ks) {                                     \
            const int _so = (((_ks * 2 + lh) ^ sx) << 4);                       \
            bf16x8 _a0 = *(const bf16x8*)(_sa + (wm * 64 + l31) * 128 + _so);   \
            bf16x8 _a1 = *(const bf16x8*)(_sa + (wm * 64 + 32 + l31) * 128 + _so); \
            bf16x8 _b0 = *(const bf16x8*)(_sb + (wn * 64 + l31) * 128 + _so);   \
            bf16x8 _b1 = *(const bf16x8*)(_sb + (wn * 64 + 32 + l31) * 128 + _so); \
            __builtin_amdgcn_s_setprio(1);                                      \
            acc[0][0] = __builtin_amdgcn_mfma_f32_32x32x16_bf16(_a0, _b0, acc[0][0], 0, 0, 0); \
            acc[0][1] = __builtin_amdgcn_mfma_f32_32x32x16_bf16(_a0, _b1, acc[0][1], 0, 0, 0); \
            acc[1][0] = __builtin_amdgcn_mfma_f32_32x32x16_bf16(_a1, _b0, acc[1][0], 0, 0, 0); \
            acc[1][1] = __builtin_amdgcn_mfma_f32_32x32x16_bf16(_a1, _b1, acc[1][1], 0, 0, 0); \
            __builtin_amdgcn_s_setprio(0);                                      \
        }                                                                       \
    } while (0)

    STAGE_T(0, 0);
    STAGE_T(1, 1);
    asm volatile("s_waitcnt vmcnt(6)" ::: "memory");
    __builtin_amdgcn_s_barrier();
    asm volatile("" ::: "memory");

    for (int kt = 0; kt < NT; ++kt) {
        if (kt + 2 < NT) STAGE_T((kt + 2) % 3, kt + 2);
        COMPUTE_T(kt % 3);
        if (kt + 2 < NT) {
            asm volatile("s_waitcnt vmcnt(6)" ::: "memory");
            __builtin_amdgcn_s_barrier();
            asm volatile("" ::: "memory");
        } else if (kt + 2 == NT) {
            asm volatile("s_waitcnt vmcnt(0)" ::: "memory");
            __builtin_amdgcn_s_barrier();
            asm volatile("" ::: "memory");
        }
    }

#undef STAGE_T
#undef COMPUTE_T

    // C map (32x32): col = lane&31, row = (reg&3) + 8*(reg>>2) + 4*(lane>>5)
    const float ds = ds_p[0];
#pragma unroll
    for (int mf = 0; mf < 2; ++mf)
#pragma unroll
        for (int reg = 0; reg < 16; ++reg) {
            const int rowl = (reg & 3) + 8 * (reg >> 2) + 4 * lh;
            const int row = m0 + wm * 64 + mf * 32 + rowl;
            const float sc = ds * rs[row];
#pragma unroll
            for (int nf = 0; nf < 2; ++nf)
                outf[(size_t)row * H_DIM + (n0 + wn * 64 + nf * 32 + l31)] =
                    sc * acc[mf][nf][reg];
        }
}

// ---------------------------------------------------------------------------
extern "C" void kernel_launch(void* const* d_in, const int* in_sizes, int n_in,
                              void* d_out, int out_size, void* d_ws, size_t ws_size,
                              hipStream_t stream) {
    const float* x   = (const float*)d_in[0];
    const int*   gp  = (const int*)d_in[1];
    const float* gs  = (const float*)d_in[2];
    const int*   upk = (const int*)d_in[3];
    const float* us  = (const float*)d_in[4];
    const int*   dp  = (const int*)d_in[5];
    const float* dsc = (const float*)d_in[6];
    const float* nw  = (const float*)d_in[7];
    float* out = (float*)d_out;

    char* ws = (char*)d_ws;
    __bf16* xb     = (__bf16*)ws;  ws += (size_t)NTOK * H_DIM * 2;
    __bf16* bgu    = (__bf16*)ws;  ws += (size_t)2 * I_DIM * H_DIM * 2;
    __bf16* wdb    = (__bf16*)ws;  ws += (size_t)H_DIM * I_DIM * 2;
    __bf16* hidden = (__bf16*)ws;  ws += (size_t)NTOK * I_DIM * 2;
    float*  rsbuf  = (float*)ws;   ws += (size_t)NTOK * 4;

    // prep
    cvt_x_kernel<<<(NTOK * H_DIM / 8 + 255) / 256, 256, 0, stream>>>(x, xb, NTOK * H_DIM / 8);
    unpack_w_kernel<<<(I_DIM * H_DIM / 8 + 255) / 256, 256, 0, stream>>>(gp, bgu, I_DIM, H_DIM, nullptr, 1);
    unpack_w_kernel<<<(I_DIM * H_DIM / 8 + 255) / 256, 256, 0, stream>>>(upk, bgu, I_DIM, H_DIM, nullptr, 2);
    unpack_w_kernel<<<(H_DIM * I_DIM / 8 + 255) / 256, 256, 0, stream>>>(dp, wdb, H_DIM, I_DIM, nw, 0);

    // gate+up fused GEMM (32x32 MFMA): grid = 32 x 54 = 1728 blocks (div by 8)
    gemm_gu32<H_DIM><<<dim3((NTOK / 256) * (2 * I_DIM / 256)), 512, 0, stream>>>(
        xb, bgu, gs, us, hidden, 2 * I_DIM / 256);

    // RMSNorm scale
    rms_rs_kernel<<<NTOK, 256, 0, stream>>>(hidden, rsbuf);

    // down GEMM (32x32 MFMA): grid = 32 x 20 = 640 blocks (div by 8)
    gemm_down_pipe<I_DIM><<<dim3((NTOK / 256) * (H_DIM / 128)), 512, 0, stream>>>(
        hidden, wdb, dsc, rsbuf, out, H_DIM / 128);
}

// Round 6
// 826.534 us; speedup vs baseline: 1.1574x; 1.1574x over previous
//
#include <hip/hip_runtime.h>
#include <cstdint>
#include <cstddef>

#define H_DIM 2560
#define I_DIM 6912
#define NTOK  8192   // B*S = 4*2048

typedef __attribute__((ext_vector_type(8))) __bf16 bf16x8;
typedef __attribute__((ext_vector_type(4))) float  f32x4;

// ---- async global->LDS, 16B per lane -------------------------------------
__device__ inline void gld16(void* lds, const void* g) {
    __builtin_amdgcn_global_load_lds(
        (__attribute__((address_space(1))) void*)(void*)g,
        (__attribute__((address_space(3))) void*)lds, 16, 0, 0);
}

// ---- prep: f32 -> bf16 (8 elems/thread) ----------------------------------
__global__ __launch_bounds__(256) void cvt_x_kernel(const float* __restrict__ x,
                                                    __bf16* __restrict__ xb, int n8) {
    int gid = blockIdx.x * 256 + threadIdx.x;
    if (gid >= n8) return;
    const float4* p = (const float4*)(x + (size_t)gid * 8);
    float4 v0 = p[0], v1 = p[1];
    bf16x8 o;
    o[0] = (__bf16)v0.x; o[1] = (__bf16)v0.y; o[2] = (__bf16)v0.z; o[3] = (__bf16)v0.w;
    o[4] = (__bf16)v1.x; o[5] = (__bf16)v1.y; o[6] = (__bf16)v1.z; o[7] = (__bf16)v1.w;
    *(bf16x8*)(xb + (size_t)gid * 8) = o;
}

// ---- prep: unpack gate+up ternary -> combined B' (16-row interleave) -------
__global__ __launch_bounds__(256) void unpack_gu_kernel(const int* __restrict__ gp,
                                                        const int* __restrict__ up,
                                                        __bf16* __restrict__ out) {
    const int per_row = H_DIM >> 3;
    const int half = I_DIM * per_row;
    int gid = blockIdx.x * 256 + threadIdx.x;
    if (gid >= 2 * half) return;
    const bool isup = gid >= half;
    const int g = isup ? gid - half : gid;
    const int* packed = isup ? up : gp;
    int i  = g / per_row;
    int k0 = (g % per_row) * 8;
    int blk = k0 >> 7;
    int grp = (k0 >> 5) & 3;
    int j0  = k0 & 31;
    int shift = 6 - 2 * grp;
    const int* p = packed + (size_t)i * (H_DIM >> 2) + blk * 32 + j0;
    int4 v0 = *(const int4*)p;
    int4 v1 = *(const int4*)(p + 4);
    int vals[8] = {v0.x, v0.y, v0.z, v0.w, v1.x, v1.y, v1.z, v1.w};
    bf16x8 o;
#pragma unroll
    for (int b = 0; b < 8; ++b)
        o[b] = (__bf16)(float)(((vals[b] >> shift) & 3) - 1);
    int dst = (i >> 4) * 32 + (i & 15) + (isup ? 16 : 0);
    *(bf16x8*)(out + (size_t)dst * H_DIM + k0) = o;
}

// ---- prep: unpack down ternary -> bf16 with norm_w fold --------------------
__global__ __launch_bounds__(256) void unpack_wd_kernel(const int* __restrict__ packed,
                                                        __bf16* __restrict__ out,
                                                        const float* __restrict__ norm) {
    const int per_row = I_DIM >> 3;
    int gid = blockIdx.x * 256 + threadIdx.x;
    if (gid >= H_DIM * per_row) return;
    int i  = gid / per_row;
    int k0 = (gid % per_row) * 8;
    int blk = k0 >> 7;
    int grp = (k0 >> 5) & 3;
    int j0  = k0 & 31;
    int shift = 6 - 2 * grp;
    const int* p = packed + (size_t)i * (I_DIM >> 2) + blk * 32 + j0;
    int4 v0 = *(const int4*)p;
    int4 v1 = *(const int4*)(p + 4);
    int vals[8] = {v0.x, v0.y, v0.z, v0.w, v1.x, v1.y, v1.z, v1.w};
    bf16x8 o;
#pragma unroll
    for (int b = 0; b < 8; ++b) {
        float f = (float)(((vals[b] >> shift) & 3) - 1);
        f *= norm[k0 + b];
        o[b] = (__bf16)f;
    }
    *(bf16x8*)(out + (size_t)i * I_DIM + k0) = o;
}

// ---- per-token rsqrt(mean(hidden^2)+eps) ----------------------------------
__global__ __launch_bounds__(256) void rms_rs_kernel(const __bf16* __restrict__ hidden,
                                                     float* __restrict__ rs) {
    const int tk = blockIdx.x;
    const __bf16* row = hidden + (size_t)tk * I_DIM;
    float s = 0.f;
    for (int idx = threadIdx.x; idx < I_DIM / 8; idx += 256) {
        bf16x8 v = *(const bf16x8*)&row[idx * 8];
#pragma unroll
        for (int j = 0; j < 8; ++j) { float f = (float)v[j]; s += f * f; }
    }
#pragma unroll
    for (int off = 32; off; off >>= 1) s += __shfl_down(s, off, 64);
    __shared__ float wsum[4];
    if ((threadIdx.x & 63) == 0) wsum[threadIdx.x >> 6] = s;
    __syncthreads();
    if (threadIdx.x == 0) {
        float tot = wsum[0] + wsum[1] + wsum[2] + wsum[3];
        rs[tk] = rsqrtf(tot / (float)I_DIM + 1e-6f);
    }
}

// ===========================================================================
// 8-phase 256x256 fused gate+up GEMM (T2+T3+T4+T5). R4-verified structure.
// BM=BN=256, BK=64, 512 thr = 8 waves (2M x 4N), per-wave 128x64 C.
// LDS 128KiB = 2 buf x {A-kk0,A-kk1 | B-nh0,B-nh1} 16KB quarters.
// Per K-tile 4 phases (kk-major); 1 half staged/phase; vmcnt(4) per tile.
// NEW (R6): explicit lgkmcnt(0)+sched_barrier(0) before each MFMA cluster.
// ===========================================================================
template<int KDIM>
__global__ __launch_bounds__(512, 2) void gemm_gu8(
    const __bf16* __restrict__ A,      // [NTOK][KDIM]
    const __bf16* __restrict__ B,      // [2*I][KDIM] gate/up 16-row interleave
    const float* __restrict__ gs_p,
    const float* __restrict__ us_p,
    __bf16* __restrict__ hidden,       // [NTOK][I_DIM]
    int nby)
{
    constexpr int KB = KDIM * 2;       // row stride bytes
    constexpr int NT = KDIM / 64;
    __shared__ __align__(16) char smem[131072];

    // bijective XCD swizzle (grid % 8 == 0)
    const int nwg = (int)gridDim.x;
    const int q = nwg >> 3;
    const int id = (int)blockIdx.x;
    const int wg = (id & 7) * q + (id >> 3);
    const int bx = wg / nby, by = wg % nby;
    const int m0 = bx * 256, n0 = by * 256;

    const int t = (int)threadIdx.x;
    const int lane = t & 63;
    const int wid = t >> 6;
    const int wm = wid >> 2, wn = wid & 3;
    const int l15 = lane & 15, s8 = lane >> 4;

    // ---- staging precompute (inverse-swizzled global src, linear LDS dest)
    const int qa  = (t & 7) ^ ((t >> 3) & 7);
    const int rA2 = ((t >> 3) << 1) + (qa >> 2);
    const char* gA0 = (const char*)A + (size_t)(m0 + rA2) * KB + (qa & 3) * 16;
    const char* gA1 = (const char*)A + (size_t)(m0 + 128 + rA2) * KB + (qa & 3) * 16;
    const int sr0 = t >> 3, sr1 = 64 + (t >> 3);
    const int br0 = ((sr0 >> 5) << 6) + (sr0 & 31);
    const int br1 = ((sr1 >> 5) << 6) + (sr1 & 31);
    const char* gB0 = (const char*)B + (size_t)(n0 + br0) * KB + qa * 16;
    const char* gB1 = (const char*)B + (size_t)(n0 + br1) * KB + qa * 16;
    char* ldst = smem + t * 16;

    // ---- compute-side read offsets (swizzled)
    const int aoff = (wm * 64 + (l15 >> 1)) * 128 +
                     (((((l15 & 1) << 2) | s8) ^ ((l15 >> 1) & 7)) << 4);
    const int boff = (wn * 32 + l15) * 128;
    const int bco0 = ((s8) ^ (l15 & 7)) << 4;
    const int bco1 = ((4 | s8) ^ (l15 & 7)) << 4;

    f32x4 acc[8][4];
#pragma unroll
    for (int f = 0; f < 8; ++f)
#pragma unroll
        for (int n = 0; n < 4; ++n) acc[f][n] = (f32x4){0, 0, 0, 0};

#define STG_A(d, kt, kk) do {                                              \
        size_t _oA = (size_t)(kt) * 128 + (kk) * 64;                       \
        gld16(ldst + (d) * 65536 + (kk) * 16384,        gA0 + _oA);        \
        gld16(ldst + (d) * 65536 + (kk) * 16384 + 8192, gA1 + _oA);        \
    } while (0)
#define STG_B(d, kt, nh) do {                                              \
        size_t _oB = (size_t)(nh) * 32 * KB + (size_t)(kt) * 128;          \
        gld16(ldst + (d) * 65536 + 32768 + (nh) * 16384,        gB0 + _oB);\
        gld16(ldst + (d) * 65536 + 32768 + (nh) * 16384 + 8192, gB1 + _oB);\
    } while (0)
#define LOAD_A(d, kk) do { _Pragma("unroll")                               \
        for (int _f = 0; _f < 8; ++_f)                                     \
            a[_f] = *(const bf16x8*)(smem + (d) * 65536 + (kk) * 16384 +   \
                                     _f * 1024 + aoff); } while (0)
#define LOAD_B(d, nh) do {                                                 \
        b0 = *(const bf16x8*)(smem + (d) * 65536 + 32768 + (nh) * 16384 +  \
                              boff + bcur);                                \
        b1 = *(const bf16x8*)(smem + (d) * 65536 + 32768 + (nh) * 16384 +  \
                              boff + bcur + 2048); } while (0)
#define MFMA16(nh) do { __builtin_amdgcn_s_setprio(1); _Pragma("unroll")   \
        for (int _f = 0; _f < 8; ++_f) {                                   \
            acc[_f][(nh) * 2] = __builtin_amdgcn_mfma_f32_16x16x32_bf16(   \
                a[_f], b0, acc[_f][(nh) * 2], 0, 0, 0);                    \
            acc[_f][(nh) * 2 + 1] = __builtin_amdgcn_mfma_f32_16x16x32_bf16(\
                a[_f], b1, acc[_f][(nh) * 2 + 1], 0, 0, 0); }              \
        __builtin_amdgcn_s_setprio(0); } while (0)
#define BAR() do { asm volatile("" ::: "memory");                          \
        __builtin_amdgcn_s_barrier();                                      \
        asm volatile("" ::: "memory"); } while (0)
#define WAITK() do { asm volatile("s_waitcnt lgkmcnt(0)" ::: "memory");    \
        __builtin_amdgcn_sched_barrier(0); } while (0)

    // ---- prologue: tile0 full + tile1 {Akk0, Bnh0}; tile0 guaranteed ------
    STG_A(0, 0, 0); STG_A(0, 0, 1); STG_B(0, 0, 0); STG_B(0, 0, 1);
    STG_A(1, 1, 0); STG_B(1, 1, 0);
    asm volatile("s_waitcnt vmcnt(4)" ::: "memory");
    BAR();

    bf16x8 a[8], b0, b1;
    for (int kt = 0; kt < NT; ++kt) {
        const int d = kt & 1;
        int bcur = bco0;
        // P1: (kk0, nh0)
        LOAD_A(d, 0); LOAD_B(d, 0);
        if (kt + 1 < NT) STG_A(d ^ 1, kt + 1, 1);
        BAR(); WAITK(); MFMA16(0); BAR();
        // P2: (kk0, nh1)
        LOAD_B(d, 1);
        if (kt + 1 < NT) STG_B(d ^ 1, kt + 1, 1);
        BAR(); WAITK(); MFMA16(1); BAR();
        // P3: (kk1, nh0)
        bcur = bco1;
        LOAD_A(d, 1); LOAD_B(d, 0);
        if (kt + 2 < NT) STG_A(d, kt + 2, 0);
        BAR(); WAITK(); MFMA16(0); BAR();
        // P4: (kk1, nh1) + tile-boundary counted vmcnt
        LOAD_B(d, 1);
        if (kt + 2 < NT) {
            STG_B(d, kt + 2, 0);
            asm volatile("s_waitcnt vmcnt(4)" ::: "memory");
        } else {
            asm volatile("s_waitcnt vmcnt(0)" ::: "memory");
        }
        BAR(); WAITK(); MFMA16(1); BAR();
    }

#undef STG_A
#undef STG_B
#undef LOAD_A
#undef LOAD_B
#undef MFMA16
#undef BAR
#undef WAITK

    // ---- epilogue: hidden = gs^2*us * relu(g)^2 * u ------------------------
    const float comb = gs_p[0] * gs_p[0] * us_p[0];
    const int r0 = m0 + wm * 128 + s8 * 4;
#pragma unroll
    for (int f = 0; f < 8; ++f)
#pragma unroll
        for (int p = 0; p < 2; ++p)
#pragma unroll
            for (int j = 0; j < 4; ++j) {
                float g = acc[f][2 * p][j];
                float u = acc[f][2 * p + 1][j];
                float r = fmaxf(g, 0.f);
                hidden[(size_t)(r0 + f * 16 + j) * I_DIM +
                       ((by * 8 + wn * 2 + p) * 16 + l15)] = (__bf16)(comb * r * r * u);
            }
}

// ===========================================================================
// Down GEMM (R3/R4-proven): BM=256, BN=128, BK=64, triple-buffer,
// depth-2 prefetch, vmcnt(6), T2 swizzle, T5 setprio, 16x16 frags.
// ===========================================================================
template<int KDIM>
__global__ __launch_bounds__(512) void gemm_down_pipe(
    const __bf16* __restrict__ A,      // hidden [NTOK][KDIM]
    const __bf16* __restrict__ B,      // Wd [H][KDIM] (norm_w folded)
    const float* __restrict__ ds_p,
    const float* __restrict__ rs,
    float* __restrict__ outf,
    int nby)
{
    constexpr int BM = 256, BN = 128, BK = 64;
    constexpr int NT = KDIM / BK;
    constexpr int SLOTB = (BM + BN) * BK * 2;
    __shared__ __align__(16) char smem[3 * SLOTB];

    const int nwg = (int)gridDim.x;
    const int q = nwg >> 3;
    const int id = (int)blockIdx.x;
    const int wg = (id & 7) * q + (id >> 3);
    const int bx = wg / nby;
    const int by = wg % nby;

    const int m0 = bx * BM;
    const int n0 = by * BN;
    const int t  = (int)threadIdx.x;
    const int lane = t & 63;
    const int wm = (t >> 6) >> 1;
    const int wn = (t >> 6) & 1;

    const int srow = t >> 3;
    const int scol = ((t & 7) * 16) ^ ((srow & 7) << 4);
    const char* gA = (const char*)A + (size_t)(m0 + srow) * (KDIM * 2) + scol;
    const char* gB = (const char*)B + (size_t)(n0 + srow) * (KDIM * 2) + scol;
    char* lbase = smem + t * 16;

    const int l15 = lane & 15;
    const int xv  = (l15 & 7) << 4;
    const int colx[2] = { (((lane >> 4) * 16) ^ xv), ((64 + (lane >> 4) * 16) ^ xv) };

    f32x4 acc[4][4];
#pragma unroll
    for (int a = 0; a < 4; ++a)
#pragma unroll
        for (int b = 0; b < 4; ++b) acc[a][b] = (f32x4){0, 0, 0, 0};

#define STAGE_T(s, kt) do {                                                     \
        char* _ls = lbase + (s) * SLOTB;                                        \
        const char* _ga = gA + (kt) * (BK * 2);                                 \
        _Pragma("unroll")                                                       \
        for (int _i = 0; _i < 4; ++_i)                                          \
            gld16(_ls + _i * 8192, _ga + (size_t)_i * 64 * (KDIM * 2));         \
        const char* _gb = gB + (kt) * (BK * 2);                                 \
        char* _lb = _ls + BM * BK * 2;                                          \
        _Pragma("unroll")                                                       \
        for (int _i = 0; _i < 2; ++_i)                                          \
            gld16(_lb + _i * 8192, _gb + (size_t)_i * 64 * (KDIM * 2));         \
    } while (0)

#define COMPUTE_T(s) do {                                                       \
        const char* _sa = smem + (s) * SLOTB;                                   \
        const char* _sb = _sa + BM * BK * 2;                                    \
        _Pragma("unroll")                                                       \
        for (int _kk = 0; _kk < 2; ++_kk) {                                     \
            bf16x8 _a[4], _b[4];                                                \
            _Pragma("unroll")                                                   \
            for (int _f = 0; _f < 4; ++_f)                                      \
                _a[_f] = *(const bf16x8*)(_sa + (wm * 64 + _f * 16 + l15) * 128 + colx[_kk]); \
            _Pragma("unroll")                                                   \
            for (int _f = 0; _f < 4; ++_f)                                      \
                _b[_f] = *(const bf16x8*)(_sb + (wn * 64 + _f * 16 + l15) * 128 + colx[_kk]); \
            __builtin_amdgcn_s_setprio(1);                                      \
            _Pragma("unroll")                                                   \
            for (int _fm = 0; _fm < 4; ++_fm)                                   \
                _Pragma("unroll")                                               \
                for (int _fn = 0; _fn < 4; ++_fn)                               \
                    acc[_fm][_fn] = __builtin_amdgcn_mfma_f32_16x16x32_bf16(    \
                        _a[_fm], _b[_fn], acc[_fm][_fn], 0, 0, 0);              \
            __builtin_amdgcn_s_setprio(0);                                      \
        }                                                                       \
    } while (0)

    STAGE_T(0, 0);
    STAGE_T(1, 1);
    asm volatile("s_waitcnt vmcnt(6)" ::: "memory");
    __builtin_amdgcn_s_barrier();
    asm volatile("" ::: "memory");

    for (int kt = 0; kt < NT; ++kt) {
        if (kt + 2 < NT) STAGE_T((kt + 2) % 3, kt + 2);
        COMPUTE_T(kt % 3);
        if (kt + 2 < NT) {
            asm volatile("s_waitcnt vmcnt(6)" ::: "memory");
            __builtin_amdgcn_s_barrier();
            asm volatile("" ::: "memory");
        } else if (kt + 2 == NT) {
            asm volatile("s_waitcnt vmcnt(0)" ::: "memory");
            __builtin_amdgcn_s_barrier();
            asm volatile("" ::: "memory");
        }
    }

#undef STAGE_T
#undef COMPUTE_T

    const float ds = ds_p[0];
    const int r0 = m0 + wm * 64 + (lane >> 4) * 4;
#pragma unroll
    for (int fm = 0; fm < 4; ++fm)
#pragma unroll
        for (int j = 0; j < 4; ++j) {
            const int row = r0 + fm * 16 + j;
            const float sc = ds * rs[row];
#pragma unroll
            for (int fn = 0; fn < 4; ++fn)
                outf[(size_t)row * H_DIM + (n0 + wn * 64 + fn * 16 + l15)] =
                    sc * acc[fm][fn][j];
        }
}

// ---------------------------------------------------------------------------
extern "C" void kernel_launch(void* const* d_in, const int* in_sizes, int n_in,
                              void* d_out, int out_size, void* d_ws, size_t ws_size,
                              hipStream_t stream) {
    const float* x   = (const float*)d_in[0];
    const int*   gp  = (const int*)d_in[1];
    const float* gs  = (const float*)d_in[2];
    const int*   upk = (const int*)d_in[3];
    const float* us  = (const float*)d_in[4];
    const int*   dp  = (const int*)d_in[5];
    const float* dsc = (const float*)d_in[6];
    const float* nw  = (const float*)d_in[7];
    float* out = (float*)d_out;

    char* ws = (char*)d_ws;
    __bf16* xb     = (__bf16*)ws;  ws += (size_t)NTOK * H_DIM * 2;
    __bf16* bgu    = (__bf16*)ws;  ws += (size_t)2 * I_DIM * H_DIM * 2;
    __bf16* wdb    = (__bf16*)ws;  ws += (size_t)H_DIM * I_DIM * 2;
    __bf16* hidden = (__bf16*)ws;  ws += (size_t)NTOK * I_DIM * 2;
    float*  rsbuf  = (float*)ws;   ws += (size_t)NTOK * 4;

    // prep
    cvt_x_kernel<<<(NTOK * H_DIM / 8 + 255) / 256, 256, 0, stream>>>(x, xb, NTOK * H_DIM / 8);
    unpack_gu_kernel<<<(2 * I_DIM * H_DIM / 8 + 255) / 256, 256, 0, stream>>>(gp, upk, bgu);
    unpack_wd_kernel<<<(H_DIM * I_DIM / 8 + 255) / 256, 256, 0, stream>>>(dp, wdb, nw);

    // gate+up fused 8-phase GEMM: grid = 32 x 54 = 1728 blocks (div by 8)
    gemm_gu8<H_DIM><<<dim3((NTOK / 256) * (2 * I_DIM / 256)), 512, 0, stream>>>(
        xb, bgu, gs, us, hidden, 2 * I_DIM / 256);

    // RMSNorm scale
    rms_rs_kernel<<<NTOK, 256, 0, stream>>>(hidden, rsbuf);

    // down GEMM: grid = 32 x 20 = 640 blocks (div by 8)
    gemm_down_pipe<I_DIM><<<dim3((NTOK / 256) * (H_DIM / 128)), 512, 0, stream>>>(
        hidden, wdb, dsc, rsbuf, out, H_DIM / 128);
}